// Round 1
// baseline (263.506 us; speedup 1.0000x reference)
//
#include <hip/hip_runtime.h>
#include <math.h>

#define NN 10000
#define GG 12
#define CC 64
#define AA 3
#define EE 50000
#define LN_EPS 1e-5f

// ---------------- kernel 1: agg init = conv_bias broadcast ----------------
__global__ __launch_bounds__(256) void init_agg(float* __restrict__ agg,
                                                const float* __restrict__ cb) {
    const int total4 = NN * GG * CC / 4;           // 1.92M float4
    int i = blockIdx.x * blockDim.x + threadIdx.x;
    const int stride = gridDim.x * blockDim.x;
    for (; i < total4; i += stride) {
        int c0 = (i * 4) & (CC - 1);
        float4 v = make_float4(cb[c0], cb[c0 + 1], cb[c0 + 2], cb[c0 + 3]);
        ((float4*)agg)[i] = v;
    }
}

// ---------------- kernel 2: depthwise fiber conv + scatter-add ----------------
// one block per edge: 12 waves (one per target g), lane = channel c
__global__ __launch_bounds__(768) void conv_scatter(
    const float* __restrict__ x, const float* __restrict__ attr,
    const float* __restrict__ Wk, const int* __restrict__ ei,
    float* __restrict__ agg) {
    __shared__ float xj[GG * CC];      // 768 floats, source-node row
    __shared__ float at[GG * GG * AA]; // 432 floats, this edge's attr

    const int e = blockIdx.x;
    const int t = threadIdx.x;
    const int src = ei[e];
    const int dst = ei[EE + e];

    xj[t] = x[src * (GG * CC) + t];
    if (t < GG * GG * AA) at[t] = attr[e * (GG * GG * AA) + t];

    const int lane = t & 63;
    const int g    = t >> 6;          // wave id = target grid point
    const float wk0 = Wk[lane];
    const float wk1 = Wk[CC + lane];
    const float wk2 = Wk[2 * CC + lane];
    __syncthreads();

    float m = 0.f;
#pragma unroll
    for (int h = 0; h < GG; ++h) {
        const float a0 = at[(g * GG + h) * AA + 0];
        const float a1 = at[(g * GG + h) * AA + 1];
        const float a2 = at[(g * GG + h) * AA + 2];
        const float k  = a0 * wk0 + a1 * wk1 + a2 * wk2;
        m = fmaf(k, xj[h * CC + lane], m);
    }
    atomicAdd(&agg[(dst * GG + g) * CC + lane], m);
}

// ---------------- kernel 3: LayerNorm + MLP(GELU) + layer_scale + residual ----------------
__device__ __forceinline__ float bcast_lane(float v, int i) {
    return __uint_as_float(__builtin_amdgcn_readlane(__float_as_uint(v), i));
}

__global__ __launch_bounds__(256) void ln_mlp(
    const float* __restrict__ agg, const float* __restrict__ x,
    const float* __restrict__ lnw, const float* __restrict__ lnb,
    const float* __restrict__ W1, const float* __restrict__ b1,
    const float* __restrict__ W2, const float* __restrict__ b2,
    const float* __restrict__ ls, float* __restrict__ out) {
    const int lane = threadIdx.x & 63;
    const int wv   = threadIdx.x >> 6;

    // per-lane column j = lane of both weight matrices, held in registers
    float w1r[CC], w2r[CC];
#pragma unroll
    for (int i = 0; i < CC; ++i) {
        w1r[i] = W1[i * CC + lane];
        w2r[i] = W2[i * CC + lane];
    }
    const float lw  = lnw[lane], lb = lnb[lane];
    const float bb1 = b1[lane],  bb2 = b2[lane];
    const float lsc = ls[lane];

    const int nf = NN * GG;                 // 120000 fibers
    const int stride = gridDim.x * 4;
    for (int f = blockIdx.x * 4 + wv; f < nf; f += stride) {
        const float v = agg[f * CC + lane];
        // LayerNorm over 64 channels (wave = fiber)
        float s = v, s2 = v * v;
#pragma unroll
        for (int off = 32; off; off >>= 1) {
            s  += __shfl_xor(s,  off);
            s2 += __shfl_xor(s2, off);
        }
        const float mu  = s * (1.f / 64.f);
        const float var = s2 * (1.f / 64.f) - mu * mu;
        const float inv = rsqrtf(var + LN_EPS);
        const float hh  = (v - mu) * inv * lw + lb;

        // h @ W1 + b1  (activation broadcast via readlane, weights in VGPRs)
        float acc = bb1;
#pragma unroll
        for (int i = 0; i < CC; ++i)
            acc = fmaf(bcast_lane(hh, i), w1r[i], acc);
        // exact GELU
        const float g1 = 0.5f * acc * (1.f + erff(acc * 0.70710678118654752f));

        float acc2 = bb2;
#pragma unroll
        for (int i = 0; i < CC; ++i)
            acc2 = fmaf(bcast_lane(g1, i), w2r[i], acc2);

        out[f * CC + lane] = fmaf(lsc, acc2, x[f * CC + lane]);
    }
}

extern "C" void kernel_launch(void* const* d_in, const int* in_sizes, int n_in,
                              void* d_out, int out_size, void* d_ws, size_t ws_size,
                              hipStream_t stream) {
    const float* x    = (const float*)d_in[0];
    const float* attr = (const float*)d_in[1];
    const float* Wk   = (const float*)d_in[2];
    const float* cb   = (const float*)d_in[3];
    const float* lnw  = (const float*)d_in[4];
    const float* lnb  = (const float*)d_in[5];
    const float* W1   = (const float*)d_in[6];
    const float* b1   = (const float*)d_in[7];
    const float* W2   = (const float*)d_in[8];
    const float* b2   = (const float*)d_in[9];
    const float* ls   = (const float*)d_in[10];
    const int*   ei   = (const int*)d_in[11];
    float* out = (float*)d_out;
    float* agg = (float*)d_ws;   // NN*GG*CC floats = 30.72 MB

    init_agg<<<1875, 256, 0, stream>>>(agg, cb);
    conv_scatter<<<EE, 768, 0, stream>>>(x, attr, Wk, ei, agg);
    ln_mlp<<<1024, 256, 0, stream>>>(agg, x, lnw, lnb, W1, b1, W2, b2, ls, out);
}

// Round 2
// 223.614 us; speedup vs baseline: 1.1784x; 1.1784x over previous
//
#include <hip/hip_runtime.h>
#include <math.h>

#define NN 10000
#define GG 12
#define CC 64
#define AA 3
#define EE 50000
#define LN_EPS 1e-5f
#define MAXDEG 64   // max in-degree; E/N = 5 expected (Poisson), 64 is far beyond max

// ---------------- kernel 1: zero per-node counters ----------------
__global__ __launch_bounds__(256) void zero_cnt(int* __restrict__ cnt) {
    int i = blockIdx.x * 256 + threadIdx.x;
    if (i < NN) cnt[i] = 0;
}

// ---------------- kernel 2: bucket edges by destination node ----------------
__global__ __launch_bounds__(256) void bucket_fill(const int* __restrict__ ei,
                                                   int* __restrict__ cnt,
                                                   int* __restrict__ elist) {
    int e = blockIdx.x * 256 + threadIdx.x;
    if (e < EE) {
        int dst = ei[EE + e];
        int pos = atomicAdd(&cnt[dst], 1);
        if (pos < MAXDEG) elist[dst * MAXDEG + pos] = e;
    }
}

// ---------------- kernel 3: fused gather-conv + LN + MLP + residual ----------------
// one block per node, 4 waves; wave wv owns grid points g = wv, wv+4, wv+8
__device__ __forceinline__ float bcast_lane(float v, int i) {
    return __uint_as_float(__builtin_amdgcn_readlane(__float_as_uint(v), i));
}

__global__ __launch_bounds__(256) void fused_node(
    const float* __restrict__ x, const float* __restrict__ attr,
    const float* __restrict__ Wk, const float* __restrict__ cb,
    const float* __restrict__ lnw, const float* __restrict__ lnb,
    const float* __restrict__ W1, const float* __restrict__ b1,
    const float* __restrict__ W2, const float* __restrict__ b2,
    const float* __restrict__ ls, const int* __restrict__ ei,
    const int* __restrict__ cnt, const int* __restrict__ elist,
    float* __restrict__ out) {
    __shared__ float xj[GG * CC];        // 768 floats: x[src] row
    __shared__ float at[GG * GG * AA];   // 432 floats: attr[e]

    const int n    = blockIdx.x;
    const int t    = threadIdx.x;
    const int lane = t & 63;
    const int wv   = t >> 6;

    const float wk0 = Wk[lane];
    const float wk1 = Wk[CC + lane];
    const float wk2 = Wk[2 * CC + lane];

    float acc[3] = {0.f, 0.f, 0.f};      // conv accumulators for g = wv, wv+4, wv+8

    const int deg = min(cnt[n], MAXDEG);
    for (int i = 0; i < deg; ++i) {
        const int e   = elist[n * MAXDEG + i];   // block-uniform -> scalar load
        const int src = ei[e];
        __syncthreads();                          // previous iter done reading LDS
        xj[t]       = x[src * (GG * CC) + t];
        xj[t + 256] = x[src * (GG * CC) + t + 256];
        xj[t + 512] = x[src * (GG * CC) + t + 512];
        if (t < 216) {
            at[t]       = attr[e * (GG * GG * AA) + t];
            at[t + 216] = attr[e * (GG * GG * AA) + t + 216];
        }
        __syncthreads();
#pragma unroll
        for (int h = 0; h < GG; ++h) {
            const float xv = xj[h * CC + lane];
#pragma unroll
            for (int j = 0; j < 3; ++j) {
                const int g = wv + 4 * j;
                const float a0 = at[(g * GG + h) * AA + 0];
                const float a1 = at[(g * GG + h) * AA + 1];
                const float a2 = at[(g * GG + h) * AA + 2];
                acc[j] = fmaf(a0 * wk0 + a1 * wk1 + a2 * wk2, xv, acc[j]);
            }
        }
    }

    // ---- epilogue: bias + LN + MLP(GELU) + layer_scale + residual ----
    const float cbv = cb[lane];
    const float lw  = lnw[lane], lb = lnb[lane];
    const float bb1 = b1[lane],  bb2 = b2[lane];
    const float lsc = ls[lane];
    float w1r[CC], w2r[CC];
#pragma unroll
    for (int i = 0; i < CC; ++i) {
        w1r[i] = W1[i * CC + lane];
        w2r[i] = W2[i * CC + lane];
    }

#pragma unroll
    for (int j = 0; j < 3; ++j) {
        const int g = wv + 4 * j;
        const float v = acc[j] + cbv;
        float s = v, s2 = v * v;
#pragma unroll
        for (int off = 32; off; off >>= 1) {
            s  += __shfl_xor(s,  off);
            s2 += __shfl_xor(s2, off);
        }
        const float mu  = s * (1.f / 64.f);
        const float var = s2 * (1.f / 64.f) - mu * mu;
        const float hh  = (v - mu) * rsqrtf(var + LN_EPS) * lw + lb;

        float a1v = bb1;
#pragma unroll
        for (int i = 0; i < CC; ++i)
            a1v = fmaf(bcast_lane(hh, i), w1r[i], a1v);
        const float g1 = 0.5f * a1v * (1.f + erff(a1v * 0.70710678118654752f));

        float a2v = bb2;
#pragma unroll
        for (int i = 0; i < CC; ++i)
            a2v = fmaf(bcast_lane(g1, i), w2r[i], a2v);

        const int idx = (n * GG + g) * CC + lane;
        out[idx] = fmaf(lsc, a2v, x[idx]);
    }
}

extern "C" void kernel_launch(void* const* d_in, const int* in_sizes, int n_in,
                              void* d_out, int out_size, void* d_ws, size_t ws_size,
                              hipStream_t stream) {
    const float* x    = (const float*)d_in[0];
    const float* attr = (const float*)d_in[1];
    const float* Wk   = (const float*)d_in[2];
    const float* cb   = (const float*)d_in[3];
    const float* lnw  = (const float*)d_in[4];
    const float* lnb  = (const float*)d_in[5];
    const float* W1   = (const float*)d_in[6];
    const float* b1   = (const float*)d_in[7];
    const float* W2   = (const float*)d_in[8];
    const float* b2   = (const float*)d_in[9];
    const float* ls   = (const float*)d_in[10];
    const int*   ei   = (const int*)d_in[11];
    float* out = (float*)d_out;

    int* cnt   = (int*)d_ws;            // NN ints
    int* elist = cnt + NN;              // NN*MAXDEG ints (2.56 MB)

    zero_cnt<<<(NN + 255) / 256, 256, 0, stream>>>(cnt);
    bucket_fill<<<(EE + 255) / 256, 256, 0, stream>>>(ei, cnt, elist);
    fused_node<<<NN, 256, 0, stream>>>(x, attr, Wk, cb, lnw, lnb, W1, b1, W2, b2,
                                       ls, ei, cnt, elist, out);
}

// Round 3
// 182.791 us; speedup vs baseline: 1.4416x; 1.2233x over previous
//
#include <hip/hip_runtime.h>
#include <math.h>

#define NN 10000
#define GG 12
#define CC 64
#define AA 3
#define EE 50000
#define LN_EPS 1e-5f
#define MAXDEG 64   // max in-degree cap; E/N = 5 expected (Poisson), 64 is far beyond max

// ---------------- kernel 1: zero per-node counters ----------------
__global__ __launch_bounds__(256) void zero_cnt(int* __restrict__ cnt) {
    int i = blockIdx.x * 256 + threadIdx.x;
    if (i < NN) cnt[i] = 0;
}

// ---------------- kernel 2: bucket edges by destination node ----------------
__global__ __launch_bounds__(256) void bucket_fill(const int* __restrict__ ei,
                                                   int* __restrict__ cnt,
                                                   int* __restrict__ elist) {
    int e = blockIdx.x * 256 + threadIdx.x;
    if (e < EE) {
        int dst = ei[EE + e];
        int pos = atomicAdd(&cnt[dst], 1);
        if (pos < MAXDEG) elist[dst * MAXDEG + pos] = e;
    }
}

// ---------------- kernel 3: conv gather (no LDS, no barriers) ----------------
// block = node, 4 waves; wave wv computes g = wv, wv+4, wv+8; lane = channel.
// attr reads are wave-uniform -> scalar pipe (s_load), consumed as SGPR fma operands.
__global__ __launch_bounds__(256) void conv_gather(
    const float* __restrict__ x, const float* __restrict__ attr,
    const float* __restrict__ Wk, const int* __restrict__ ei,
    const int* __restrict__ cnt, const int* __restrict__ elist,
    float* __restrict__ agg) {
    const int n    = blockIdx.x;
    const int lane = threadIdx.x & 63;
    const int wv   = __builtin_amdgcn_readfirstlane(threadIdx.x >> 6);

    const float wk0 = Wk[lane];
    const float wk1 = Wk[CC + lane];
    const float wk2 = Wk[2 * CC + lane];

    float acc[3] = {0.f, 0.f, 0.f};
    const int deg = min(cnt[n], MAXDEG);

    for (int i = 0; i < deg; ++i) {
        const int e   = __builtin_amdgcn_readfirstlane(elist[n * MAXDEG + i]);
        const int src = __builtin_amdgcn_readfirstlane(ei[e]);

        // source-node row, channel `lane`, all 12 grid points -> 12 VGPRs
        const float* xrow = x + src * (GG * CC) + lane;
        float xr[GG];
#pragma unroll
        for (int h = 0; h < GG; ++h) xr[h] = xrow[h * CC];

        const float* ap = attr + (size_t)e * (GG * GG * AA);
#pragma unroll
        for (int j = 0; j < 3; ++j) {
            const float* bp = ap + (wv + 4 * j) * (GG * AA);  // uniform -> s_load
            float t0 = 0.f, t1 = 0.f, t2 = 0.f;
#pragma unroll
            for (int h = 0; h < GG; ++h) {
                const float xv = xr[h];
                t0 = fmaf(bp[h * 3 + 0], xv, t0);
                t1 = fmaf(bp[h * 3 + 1], xv, t1);
                t2 = fmaf(bp[h * 3 + 2], xv, t2);
            }
            acc[j] = fmaf(t0, wk0, fmaf(t1, wk1, fmaf(t2, wk2, acc[j])));
        }
    }

    agg[(n * GG + wv) * CC + lane]      = acc[0];
    agg[(n * GG + wv + 4) * CC + lane]  = acc[1];
    agg[(n * GG + wv + 8) * CC + lane]  = acc[2];
}

// ---------------- kernel 4: LN + MLP(GELU) + layer_scale + residual ----------------
// weights register-resident (128 VGPR), amortized over ~59 fibers per wave.
// Reads agg in-place from the output buffer (each wave reads its fiber before writing).
__device__ __forceinline__ float bcast_lane(float v, int i) {
    return __uint_as_float(__builtin_amdgcn_readlane(__float_as_uint(v), i));
}

__global__ __launch_bounds__(256, 2) void ln_mlp(
    const float* __restrict__ x, const float* __restrict__ cb,
    const float* __restrict__ lnw, const float* __restrict__ lnb,
    const float* __restrict__ W1, const float* __restrict__ b1,
    const float* __restrict__ W2, const float* __restrict__ b2,
    const float* __restrict__ ls, float* __restrict__ out) {
    const int lane = threadIdx.x & 63;
    const int wv   = threadIdx.x >> 6;

    float w1r[CC], w2r[CC];
#pragma unroll
    for (int i = 0; i < CC; ++i) {
        w1r[i] = W1[i * CC + lane];
        w2r[i] = W2[i * CC + lane];
    }
    const float cbv = cb[lane];
    const float lw  = lnw[lane], lb = lnb[lane];
    const float bb1 = b1[lane],  bb2 = b2[lane];
    const float lsc = ls[lane];

    const int nf = NN * GG;
    const int nw = gridDim.x * 4;
    for (int f = blockIdx.x * 4 + wv; f < nf; f += nw) {
        const float v = out[f * CC + lane] + cbv;   // agg was written here by conv_gather
        float s = v, s2 = v * v;
#pragma unroll
        for (int off = 32; off; off >>= 1) {
            s  += __shfl_xor(s,  off);
            s2 += __shfl_xor(s2, off);
        }
        const float mu  = s * (1.f / 64.f);
        const float var = s2 * (1.f / 64.f) - mu * mu;
        const float hh  = (v - mu) * rsqrtf(var + LN_EPS) * lw + lb;

        float a0 = 0.f, a1 = 0.f, a2 = 0.f, a3 = 0.f;
#pragma unroll
        for (int i = 0; i < CC; i += 4) {
            a0 = fmaf(bcast_lane(hh, i),     w1r[i],     a0);
            a1 = fmaf(bcast_lane(hh, i + 1), w1r[i + 1], a1);
            a2 = fmaf(bcast_lane(hh, i + 2), w1r[i + 2], a2);
            a3 = fmaf(bcast_lane(hh, i + 3), w1r[i + 3], a3);
        }
        const float z  = ((a0 + a1) + (a2 + a3)) + bb1;
        const float gl = 0.5f * z * (1.f + erff(z * 0.70710678118654752f));

        float c0 = 0.f, c1 = 0.f, c2 = 0.f, c3 = 0.f;
#pragma unroll
        for (int i = 0; i < CC; i += 4) {
            c0 = fmaf(bcast_lane(gl, i),     w2r[i],     c0);
            c1 = fmaf(bcast_lane(gl, i + 1), w2r[i + 1], c1);
            c2 = fmaf(bcast_lane(gl, i + 2), w2r[i + 2], c2);
            c3 = fmaf(bcast_lane(gl, i + 3), w2r[i + 3], c3);
        }
        const float z2 = ((c0 + c1) + (c2 + c3)) + bb2;

        out[f * CC + lane] = fmaf(lsc, z2, x[f * CC + lane]);
    }
}

extern "C" void kernel_launch(void* const* d_in, const int* in_sizes, int n_in,
                              void* d_out, int out_size, void* d_ws, size_t ws_size,
                              hipStream_t stream) {
    const float* x    = (const float*)d_in[0];
    const float* attr = (const float*)d_in[1];
    const float* Wk   = (const float*)d_in[2];
    const float* cb   = (const float*)d_in[3];
    const float* lnw  = (const float*)d_in[4];
    const float* lnb  = (const float*)d_in[5];
    const float* W1   = (const float*)d_in[6];
    const float* b1   = (const float*)d_in[7];
    const float* W2   = (const float*)d_in[8];
    const float* b2   = (const float*)d_in[9];
    const float* ls   = (const float*)d_in[10];
    const int*   ei   = (const int*)d_in[11];
    float* out = (float*)d_out;

    int* cnt   = (int*)d_ws;            // NN ints
    int* elist = cnt + NN;              // NN*MAXDEG ints (2.56 MB)

    zero_cnt<<<(NN + 255) / 256, 256, 0, stream>>>(cnt);
    bucket_fill<<<(EE + 255) / 256, 256, 0, stream>>>(ei, cnt, elist);
    // conv result goes straight into d_out; ln_mlp rewrites it in place
    conv_gather<<<NN, 256, 0, stream>>>(x, attr, Wk, ei, cnt, elist, out);
    ln_mlp<<<512, 256, 0, stream>>>(x, cb, lnw, lnb, W1, b1, W2, b2, ls, out);
}

// Round 4
// 179.723 us; speedup vs baseline: 1.4662x; 1.0171x over previous
//
#include <hip/hip_runtime.h>
#include <math.h>

#define NN 10000
#define GG 12
#define CC 64
#define AA 3
#define EE 50000
#define LN_EPS 1e-5f
#define MAXDEG 64   // max in-degree cap; Poisson(E/N=5) max ~17, 64 is far beyond

__device__ __forceinline__ int rfl(int v) { return __builtin_amdgcn_readfirstlane(v); }
__device__ __forceinline__ float bcast_lane(float v, int i) {
    return __uint_as_float(__builtin_amdgcn_readlane(__float_as_uint(v), i));
}

// ---------------- kernel 1: zero per-node counters ----------------
__global__ __launch_bounds__(256) void zero_cnt(int* __restrict__ cnt) {
    int i = blockIdx.x * 256 + threadIdx.x;
    if (i < NN) cnt[i] = 0;
}

// ---------------- kernel 2: bucket edges by destination; pack e | src<<17 ----------------
__global__ __launch_bounds__(256) void bucket_fill(const int* __restrict__ ei,
                                                   int* __restrict__ cnt,
                                                   int* __restrict__ elist) {
    int e = blockIdx.x * 256 + threadIdx.x;
    if (e < EE) {
        int src = ei[e];
        int dst = ei[EE + e];
        int pos = atomicAdd(&cnt[dst], 1);
        if (pos < MAXDEG) elist[dst * MAXDEG + pos] = e | (src << 17);
    }
}

// ---------------- kernel 3: conv gather, software-pipelined ----------------
// block = node, 8 waves: wave = (edge-parity ew, g-triple gw). lane = channel.
// Next edge's index+x-row prefetched during current edge's compute.
// attr reads are wave-uniform -> scalar pipe s_loads feeding v_fma directly.
__global__ __launch_bounds__(512) void conv_gather(
    const float* __restrict__ x, const float* __restrict__ attr,
    const float* __restrict__ Wk,
    const int* __restrict__ cnt, const int* __restrict__ elist,
    float* __restrict__ agg) {
    __shared__ float red[4][3][CC];            // 3 KB: edge-parity-1 partials

    const int n    = blockIdx.x;
    const int t    = threadIdx.x;
    const int lane = t & 63;
    const int w    = rfl(t >> 6);
    const int gw   = w & 3;                    // g = gw, gw+4, gw+8
    const int ew   = w >> 2;                   // edge parity 0/1

    const float wk0 = Wk[lane];
    const float wk1 = Wk[CC + lane];
    const float wk2 = Wk[2 * CC + lane];

    float acc[3] = {0.f, 0.f, 0.f};
    const int deg = min(cnt[n], MAXDEG);

    int i = ew;
    int e0 = 0;
    float xr0[GG];
    if (i < deg) {                             // wave-uniform branch
        const int p   = rfl(elist[n * MAXDEG + i]);
        e0 = p & 0x1FFFF;
        const float* xp = x + (p >> 17) * (GG * CC) + lane;
#pragma unroll
        for (int h = 0; h < GG; ++h) xr0[h] = xp[h * CC];
    }

    for (; i < deg; i += 2) {
        // ---- prefetch edge i+2 (index + x row) while computing edge i ----
        int e1 = 0;
        float xr1[GG];
        if (i + 2 < deg) {
            const int p   = rfl(elist[n * MAXDEG + i + 2]);
            e1 = p & 0x1FFFF;
            const float* xp = x + (p >> 17) * (GG * CC) + lane;
#pragma unroll
            for (int h = 0; h < GG; ++h) xr1[h] = xp[h * CC];
        }

        // ---- compute edge i: attr via scalar loads (uniform address) ----
        const float* ap = attr + (size_t)e0 * (GG * GG * AA);
#pragma unroll
        for (int j = 0; j < 3; ++j) {
            const float* bp = ap + (gw + 4 * j) * (GG * AA);
            float t0 = 0.f, t1 = 0.f, t2 = 0.f;
#pragma unroll
            for (int h = 0; h < GG; ++h) {
                const float xv = xr0[h];
                t0 = fmaf(bp[h * 3 + 0], xv, t0);
                t1 = fmaf(bp[h * 3 + 1], xv, t1);
                t2 = fmaf(bp[h * 3 + 2], xv, t2);
            }
            acc[j] = fmaf(t0, wk0, fmaf(t1, wk1, fmaf(t2, wk2, acc[j])));
        }

        e0 = e1;
#pragma unroll
        for (int h = 0; h < GG; ++h) xr0[h] = xr1[h];
    }

    // ---- cross-parity reduction + store ----
    if (ew == 1) {
#pragma unroll
        for (int j = 0; j < 3; ++j) red[gw][j][lane] = acc[j];
    }
    __syncthreads();
    if (ew == 0) {
#pragma unroll
        for (int j = 0; j < 3; ++j)
            agg[(n * GG + gw + 4 * j) * CC + lane] = acc[j] + red[gw][j][lane];
    }
}

// ---------------- kernel 4: LN + MLP(GELU) + layer_scale + residual ----------------
__global__ __launch_bounds__(256, 2) void ln_mlp(
    const float* __restrict__ x, const float* __restrict__ cb,
    const float* __restrict__ lnw, const float* __restrict__ lnb,
    const float* __restrict__ W1, const float* __restrict__ b1,
    const float* __restrict__ W2, const float* __restrict__ b2,
    const float* __restrict__ ls, float* __restrict__ out) {
    const int lane = threadIdx.x & 63;
    const int wv   = threadIdx.x >> 6;

    float w1r[CC], w2r[CC];
#pragma unroll
    for (int i = 0; i < CC; ++i) {
        w1r[i] = W1[i * CC + lane];
        w2r[i] = W2[i * CC + lane];
    }
    const float cbv = cb[lane];
    const float lw  = lnw[lane], lb = lnb[lane];
    const float bb1 = b1[lane],  bb2 = b2[lane];
    const float lsc = ls[lane];

    const int nf = NN * GG;
    const int nw = gridDim.x * 4;
    for (int f = blockIdx.x * 4 + wv; f < nf; f += nw) {
        const float v = out[f * CC + lane] + cbv;   // agg written here by conv_gather
        float s = v, s2 = v * v;
#pragma unroll
        for (int off = 32; off; off >>= 1) {
            s  += __shfl_xor(s,  off);
            s2 += __shfl_xor(s2, off);
        }
        const float mu  = s * (1.f / 64.f);
        const float var = s2 * (1.f / 64.f) - mu * mu;
        const float hh  = (v - mu) * rsqrtf(var + LN_EPS) * lw + lb;

        float a0 = 0.f, a1 = 0.f, a2 = 0.f, a3 = 0.f;
#pragma unroll
        for (int i = 0; i < CC; i += 4) {
            a0 = fmaf(bcast_lane(hh, i),     w1r[i],     a0);
            a1 = fmaf(bcast_lane(hh, i + 1), w1r[i + 1], a1);
            a2 = fmaf(bcast_lane(hh, i + 2), w1r[i + 2], a2);
            a3 = fmaf(bcast_lane(hh, i + 3), w1r[i + 3], a3);
        }
        const float z  = ((a0 + a1) + (a2 + a3)) + bb1;
        const float gl = 0.5f * z * (1.f + erff(z * 0.70710678118654752f));

        float c0 = 0.f, c1 = 0.f, c2 = 0.f, c3 = 0.f;
#pragma unroll
        for (int i = 0; i < CC; i += 4) {
            c0 = fmaf(bcast_lane(gl, i),     w2r[i],     c0);
            c1 = fmaf(bcast_lane(gl, i + 1), w2r[i + 1], c1);
            c2 = fmaf(bcast_lane(gl, i + 2), w2r[i + 2], c2);
            c3 = fmaf(bcast_lane(gl, i + 3), w2r[i + 3], c3);
        }
        const float z2 = ((c0 + c1) + (c2 + c3)) + bb2;

        out[f * CC + lane] = fmaf(lsc, z2, x[f * CC + lane]);
    }
}

extern "C" void kernel_launch(void* const* d_in, const int* in_sizes, int n_in,
                              void* d_out, int out_size, void* d_ws, size_t ws_size,
                              hipStream_t stream) {
    const float* x    = (const float*)d_in[0];
    const float* attr = (const float*)d_in[1];
    const float* Wk   = (const float*)d_in[2];
    const float* cb   = (const float*)d_in[3];
    const float* lnw  = (const float*)d_in[4];
    const float* lnb  = (const float*)d_in[5];
    const float* W1   = (const float*)d_in[6];
    const float* b1   = (const float*)d_in[7];
    const float* W2   = (const float*)d_in[8];
    const float* b2   = (const float*)d_in[9];
    const float* ls   = (const float*)d_in[10];
    const int*   ei   = (const int*)d_in[11];
    float* out = (float*)d_out;

    int* cnt   = (int*)d_ws;            // NN ints
    int* elist = cnt + NN;              // NN*MAXDEG ints (2.56 MB)

    zero_cnt<<<(NN + 255) / 256, 256, 0, stream>>>(cnt);
    bucket_fill<<<(EE + 255) / 256, 256, 0, stream>>>(ei, cnt, elist);
    conv_gather<<<NN, 512, 0, stream>>>(x, attr, Wk, cnt, elist, out);
    ln_mlp<<<512, 256, 0, stream>>>(x, cb, lnw, lnb, W1, b1, W2, b2, ls, out);
}